// Round 1
// baseline (947.018 us; speedup 1.0000x reference)
//
#include <hip/hip_runtime.h>
#include <hip/hip_bf16.h>

#define IN_DIM  512
#define HID     1024
#define OUT_DIM 512
#define BATCH   4096
#define T_STEPS 32

typedef __attribute__((ext_vector_type(8))) short bf16x8;
typedef __attribute__((ext_vector_type(4))) float f32x4;

__device__ inline void gload16(const void* g, void* l) {
  __builtin_amdgcn_global_load_lds(
      (const __attribute__((address_space(1))) void*)g,
      (__attribute__((address_space(3))) void*)l, 16, 0, 0);
}

// D[b][i] = sum_k A[b][k] * B[i][k], then relu(D + bias[i]).
// A: [Mtotal=4096][K] bf16 row-major (h^T or x^T)
// B: [Ntotal][K]      bf16 row-major (W as stored)
// Cf: f32, written TRANSPOSED: Cf[i*4096 + b]  (intermediate / out layout [H][B])
// Cb: bf16, written natural:   Cb[b*Nld + i]   (h^T scratch for next step), may be null
__global__ __launch_bounds__(256) void gemm_bt_bias_relu(
    const __hip_bfloat16* __restrict__ A,
    const __hip_bfloat16* __restrict__ B,
    const float* __restrict__ bias,
    float* __restrict__ Cf,
    __hip_bfloat16* __restrict__ Cb,
    int K, int Nld)
{
  const int tid  = threadIdx.x;
  const int lane = tid & 63;
  const int wid  = tid >> 6;
  const int wr   = wid >> 1, wc = wid & 1;       // 2x2 waves, each 64x64
  const int brow = blockIdx.y * 128;             // b (batch) offset
  const int bcol = blockIdx.x * 128;             // i (neuron) offset
  const int l15  = lane & 15, l4 = lane >> 4;

  __shared__ __hip_bfloat16 Alds[128 * 64];
  __shared__ __hip_bfloat16 Blds[128 * 64];

  f32x4 acc[4][4] = {};

  for (int kt = 0; kt < K; kt += 64) {
#pragma unroll
    for (int it = 0; it < 4; ++it) {
      const int flat = it * 256 + tid;
      const int row = flat >> 3, chunk = flat & 7;        // 8 x 16B chunks per 64-elem row
      const int ldsbase = (it * 256 + wid * 64) * 8;      // wave-uniform base (elements)
      gload16(A + (size_t)(brow + row) * K + kt + chunk * 8, &Alds[ldsbase]);
      gload16(B + (size_t)(bcol + row) * K + kt + chunk * 8, &Blds[ldsbase]);
    }
    __syncthreads();   // drains vmcnt(0) + barrier
#pragma unroll
    for (int ks = 0; ks < 2; ++ks) {
      bf16x8 af[4], bfr[4];
#pragma unroll
      for (int m = 0; m < 4; ++m)
        af[m] = *(const bf16x8*)&Alds[(wr * 64 + m * 16 + l15) * 64 + ks * 32 + l4 * 8];
#pragma unroll
      for (int n = 0; n < 4; ++n)
        bfr[n] = *(const bf16x8*)&Blds[(wc * 64 + n * 16 + l15) * 64 + ks * 32 + l4 * 8];
#pragma unroll
      for (int m = 0; m < 4; ++m)
#pragma unroll
        for (int n = 0; n < 4; ++n)
          acc[m][n] = __builtin_amdgcn_mfma_f32_16x16x32_bf16(af[m], bfr[n], acc[m][n], 0, 0, 0);
    }
    __syncthreads();
  }

  // epilogue: bias + relu, dual store
#pragma unroll
  for (int n = 0; n < 4; ++n) {
    const int i = bcol + wc * 64 + n * 16 + l15;
    const float bv = bias[i];
#pragma unroll
    for (int m = 0; m < 4; ++m) {
      const int b0 = brow + wr * 64 + m * 16 + l4 * 4;
      f32x4 v = acc[m][n];
      float4 o;
      o.x = fmaxf(v[0] + bv, 0.0f);
      o.y = fmaxf(v[1] + bv, 0.0f);
      o.z = fmaxf(v[2] + bv, 0.0f);
      o.w = fmaxf(v[3] + bv, 0.0f);
      *(float4*)(Cf + (size_t)i * BATCH + b0) = o;   // 16B/lane, 64B-sector coalesced
      if (Cb) {
        Cb[(size_t)(b0 + 0) * Nld + i] = __float2bfloat16(o.x);
        Cb[(size_t)(b0 + 1) * Nld + i] = __float2bfloat16(o.y);
        Cb[(size_t)(b0 + 2) * Nld + i] = __float2bfloat16(o.z);
        Cb[(size_t)(b0 + 3) * Nld + i] = __float2bfloat16(o.w);
      }
    }
  }
}

// plain f32 -> bf16 convert (vectorized), n4 = count/4
__global__ __launch_bounds__(256) void f32_to_bf16(
    const float* __restrict__ in, __hip_bfloat16* __restrict__ out, int n4)
{
  int i = blockIdx.x * blockDim.x + threadIdx.x;
  if (i < n4) {
    float4 v = ((const float4*)in)[i];
    union { __hip_bfloat16 h[4]; ushort4 u; } p;
    p.h[0] = __float2bfloat16(v.x);
    p.h[1] = __float2bfloat16(v.y);
    p.h[2] = __float2bfloat16(v.z);
    p.h[3] = __float2bfloat16(v.w);
    ((ushort4*)out)[i] = p.u;
  }
}

// in[R][C] f32 -> out[C][R] bf16 (LDS 32x32 tile transpose)
__global__ __launch_bounds__(256) void transpose_f32_bf16(
    const float* __restrict__ in, __hip_bfloat16* __restrict__ out, int R, int C)
{
  __shared__ float tile[32][33];
  const int c0 = blockIdx.x * 32, r0 = blockIdx.y * 32;
  const int tx = threadIdx.x & 31, ty = threadIdx.x >> 5;
#pragma unroll
  for (int dy = 0; dy < 32; dy += 8)
    tile[ty + dy][tx] = in[(size_t)(r0 + ty + dy) * C + c0 + tx];
  __syncthreads();
#pragma unroll
  for (int dy = 0; dy < 32; dy += 8)
    out[(size_t)(c0 + ty + dy) * R + r0 + tx] = __float2bfloat16(tile[tx][ty + dy]);
}

extern "C" void kernel_launch(void* const* d_in, const int* in_sizes, int n_in,
                              void* d_out, int out_size, void* d_ws, size_t ws_size,
                              hipStream_t stream)
{
  const float* x     = (const float*)d_in[0];   // [512][4096]
  const float* W_in  = (const float*)d_in[1];   // [1024][512]
  const float* b_in  = (const float*)d_in[2];   // [1024]
  const float* W_rec = (const float*)d_in[3];   // [1024][1024]
  const float* b_rec = (const float*)d_in[4];   // [1024]
  const float* W_out = (const float*)d_in[5];   // [512][1024]
  const float* b_out = (const float*)d_in[6];   // [512]

  float* out0 = (float*)d_out;                        // [512][4096]
  float* itm  = out0 + (size_t)OUT_DIM * BATCH;       // [33][1024][4096]

  __hip_bfloat16* xT = (__hip_bfloat16*)d_ws;         // [4096][512]
  __hip_bfloat16* Wi = xT + (size_t)BATCH * IN_DIM;   // [1024][512]
  __hip_bfloat16* Wr = Wi + (size_t)HID * IN_DIM;     // [1024][1024]
  __hip_bfloat16* Wo = Wr + (size_t)HID * HID;        // [512][1024]
  __hip_bfloat16* h0 = Wo + (size_t)OUT_DIM * HID;    // [4096][1024]
  __hip_bfloat16* h1 = h0 + (size_t)BATCH * HID;      // [4096][1024]

  // input conversions
  transpose_f32_bf16<<<dim3(BATCH / 32, IN_DIM / 32), 256, 0, stream>>>(x, xT, IN_DIM, BATCH);
  {
    int n4 = HID * IN_DIM / 4;
    f32_to_bf16<<<(n4 + 255) / 256, 256, 0, stream>>>(W_in, Wi, n4);
  }
  {
    int n4 = HID * HID / 4;
    f32_to_bf16<<<(n4 + 255) / 256, 256, 0, stream>>>(W_rec, Wr, n4);
  }
  {
    int n4 = OUT_DIM * HID / 4;
    f32_to_bf16<<<(n4 + 255) / 256, 256, 0, stream>>>(W_out, Wo, n4);
  }

  // y0 = relu(W_in @ x + b_in): A=xT [4096][512], B=W_in [1024][512]
  gemm_bt_bias_relu<<<dim3(HID / 128, BATCH / 128), 256, 0, stream>>>(
      xT, Wi, b_in, itm, h0, IN_DIM, HID);

  // 32 recurrent steps
  __hip_bfloat16* cur = h0;
  __hip_bfloat16* nxt = h1;
  for (int t = 0; t < T_STEPS; ++t) {
    float* dst = itm + (size_t)(t + 1) * HID * BATCH;
    gemm_bt_bias_relu<<<dim3(HID / 128, BATCH / 128), 256, 0, stream>>>(
        cur, Wr, b_rec, dst, nxt, HID, HID);
    __hip_bfloat16* tmp = cur; cur = nxt; nxt = tmp;
  }

  // out = relu(W_out @ h_last + b_out): B=W_out [512][1024]
  gemm_bt_bias_relu<<<dim3(OUT_DIM / 128, BATCH / 128), 256, 0, stream>>>(
      cur, Wo, b_out, out0, (__hip_bfloat16*)nullptr, HID, 0);
}

// Round 2
// 789.963 us; speedup vs baseline: 1.1988x; 1.1988x over previous
//
#include <hip/hip_runtime.h>
#include <hip/hip_bf16.h>

#define IN_DIM  512
#define HID     1024
#define OUT_DIM 512
#define BATCH   4096
#define T_STEPS 32

typedef __attribute__((ext_vector_type(8))) short bf16x8;
typedef __attribute__((ext_vector_type(4))) float f32x4;

__device__ inline void gload16(const void* g, void* l) {
  __builtin_amdgcn_global_load_lds(
      (const __attribute__((address_space(1))) void*)g,
      (__attribute__((address_space(3))) void*)l, 16, 0, 0);
}

// D[b][i] = sum_k A[b][k] * B[i][k], then relu(D + bias[i]).
// Tile: 128 (batch) x 64 (neurons), BK=64, 4 waves each 64x32.
// A: [4096][K] bf16 row-major (h^T or x^T)
// B: [Ntot][K] bf16 row-major (W as stored, k-contiguous)
// Cf: f32 written transposed: Cf[i*BATCH + b]   (intermediate/out layout [H][B])
// Cb: bf16 written natural:   Cb[b*Nld + i]     (h^T scratch for next step), may be null
__global__ __launch_bounds__(256, 2) void gemm_bt_bias_relu(
    const __hip_bfloat16* __restrict__ A,
    const __hip_bfloat16* __restrict__ B,
    const float* __restrict__ bias,
    float* __restrict__ Cf,
    __hip_bfloat16* __restrict__ Cb,
    int K, int Nld)
{
  const int tid  = threadIdx.x;
  const int lane = tid & 63;
  const int wid  = tid >> 6;
  const int wr   = wid >> 1, wc = wid & 1;   // 2x2 waves: wave tile 64(b) x 32(i)
  const int brow = blockIdx.y * 128;         // batch offset
  const int bcol = blockIdx.x * 64;          // neuron offset
  const int l15  = lane & 15, l4 = lane >> 4;
  const int srow = lane >> 3, schunk = lane & 7;  // staging: 8 lanes per 64-elem row

  __shared__ __hip_bfloat16 Alds[128 * 64];  // 16 KB
  __shared__ __hip_bfloat16 Blds[64 * 64];   //  8 KB

  f32x4 acc[4][2] = {};

  for (int kt = 0; kt < K; kt += 64) {
    // ---- stage A: 128 rows, 4 rounds of 32 rows (8 rows per wave) ----
#pragma unroll
    for (int it = 0; it < 4; ++it) {
      const int rowbase = it * 32 + wid * 8;            // wave-uniform
      gload16(A + (size_t)(brow + rowbase + srow) * K + kt + schunk * 8,
              &Alds[rowbase * 64]);
    }
    // ---- stage B: 64 rows, 2 rounds ----
#pragma unroll
    for (int it = 0; it < 2; ++it) {
      const int rowbase = it * 32 + wid * 8;
      gload16(B + (size_t)(bcol + rowbase + srow) * K + kt + schunk * 8,
              &Blds[rowbase * 64]);
    }
    __syncthreads();   // vmcnt(0) drain + barrier
#pragma unroll
    for (int ks = 0; ks < 2; ++ks) {
      bf16x8 af[4], bfr[2];
#pragma unroll
      for (int m = 0; m < 4; ++m)
        af[m] = *(const bf16x8*)&Alds[(wr * 64 + m * 16 + l15) * 64 + ks * 32 + l4 * 8];
#pragma unroll
      for (int n = 0; n < 2; ++n)
        bfr[n] = *(const bf16x8*)&Blds[(wc * 32 + n * 16 + l15) * 64 + ks * 32 + l4 * 8];
#pragma unroll
      for (int m = 0; m < 4; ++m)
#pragma unroll
        for (int n = 0; n < 2; ++n)
          acc[m][n] = __builtin_amdgcn_mfma_f32_16x16x32_bf16(af[m], bfr[n], acc[m][n], 0, 0, 0);
    }
    __syncthreads();
  }

  // epilogue: bias + relu, dual store
#pragma unroll
  for (int n = 0; n < 2; ++n) {
    const int i = bcol + wc * 32 + n * 16 + l15;
    const float bv = bias[i];
#pragma unroll
    for (int m = 0; m < 4; ++m) {
      const int b0 = brow + wr * 64 + m * 16 + l4 * 4;
      f32x4 v = acc[m][n];
      float4 o;
      o.x = fmaxf(v[0] + bv, 0.0f);
      o.y = fmaxf(v[1] + bv, 0.0f);
      o.z = fmaxf(v[2] + bv, 0.0f);
      o.w = fmaxf(v[3] + bv, 0.0f);
      *(float4*)(Cf + (size_t)i * BATCH + b0) = o;   // 16B/lane, coalesced per 16-lane group
      if (Cb) {
        Cb[(size_t)(b0 + 0) * Nld + i] = __float2bfloat16(o.x);
        Cb[(size_t)(b0 + 1) * Nld + i] = __float2bfloat16(o.y);
        Cb[(size_t)(b0 + 2) * Nld + i] = __float2bfloat16(o.z);
        Cb[(size_t)(b0 + 3) * Nld + i] = __float2bfloat16(o.w);
      }
    }
  }
}

// plain f32 -> bf16 convert (vectorized), n4 = count/4
__global__ __launch_bounds__(256) void f32_to_bf16(
    const float* __restrict__ in, __hip_bfloat16* __restrict__ out, int n4)
{
  int i = blockIdx.x * blockDim.x + threadIdx.x;
  if (i < n4) {
    float4 v = ((const float4*)in)[i];
    union { __hip_bfloat16 h[4]; ushort4 u; } p;
    p.h[0] = __float2bfloat16(v.x);
    p.h[1] = __float2bfloat16(v.y);
    p.h[2] = __float2bfloat16(v.z);
    p.h[3] = __float2bfloat16(v.w);
    ((ushort4*)out)[i] = p.u;
  }
}

// in[R][C] f32 -> out[C][R] bf16 (LDS 32x32 tile transpose)
__global__ __launch_bounds__(256) void transpose_f32_bf16(
    const float* __restrict__ in, __hip_bfloat16* __restrict__ out, int R, int C)
{
  __shared__ float tile[32][33];
  const int c0 = blockIdx.x * 32, r0 = blockIdx.y * 32;
  const int tx = threadIdx.x & 31, ty = threadIdx.x >> 5;
#pragma unroll
  for (int dy = 0; dy < 32; dy += 8)
    tile[ty + dy][tx] = in[(size_t)(r0 + ty + dy) * C + c0 + tx];
  __syncthreads();
#pragma unroll
  for (int dy = 0; dy < 32; dy += 8)
    out[(size_t)(c0 + ty + dy) * R + r0 + tx] = __float2bfloat16(tile[tx][ty + dy]);
}

extern "C" void kernel_launch(void* const* d_in, const int* in_sizes, int n_in,
                              void* d_out, int out_size, void* d_ws, size_t ws_size,
                              hipStream_t stream)
{
  const float* x     = (const float*)d_in[0];   // [512][4096]
  const float* W_in  = (const float*)d_in[1];   // [1024][512]
  const float* b_in  = (const float*)d_in[2];   // [1024]
  const float* W_rec = (const float*)d_in[3];   // [1024][1024]
  const float* b_rec = (const float*)d_in[4];   // [1024]
  const float* W_out = (const float*)d_in[5];   // [512][1024]
  const float* b_out = (const float*)d_in[6];   // [512]

  float* out0 = (float*)d_out;                        // [512][4096]
  float* itm  = out0 + (size_t)OUT_DIM * BATCH;       // [33][1024][4096]

  __hip_bfloat16* xT = (__hip_bfloat16*)d_ws;         // [4096][512]
  __hip_bfloat16* Wi = xT + (size_t)BATCH * IN_DIM;   // [1024][512]
  __hip_bfloat16* Wr = Wi + (size_t)HID * IN_DIM;     // [1024][1024]
  __hip_bfloat16* Wo = Wr + (size_t)HID * HID;        // [512][1024]
  __hip_bfloat16* h0 = Wo + (size_t)OUT_DIM * HID;    // [4096][1024]
  __hip_bfloat16* h1 = h0 + (size_t)BATCH * HID;      // [4096][1024]

  // input conversions
  transpose_f32_bf16<<<dim3(BATCH / 32, IN_DIM / 32), 256, 0, stream>>>(x, xT, IN_DIM, BATCH);
  {
    int n4 = HID * IN_DIM / 4;
    f32_to_bf16<<<(n4 + 255) / 256, 256, 0, stream>>>(W_in, Wi, n4);
  }
  {
    int n4 = HID * HID / 4;
    f32_to_bf16<<<(n4 + 255) / 256, 256, 0, stream>>>(W_rec, Wr, n4);
  }
  {
    int n4 = OUT_DIM * HID / 4;
    f32_to_bf16<<<(n4 + 255) / 256, 256, 0, stream>>>(W_out, Wo, n4);
  }

  // y0 = relu(W_in @ x + b_in): A=xT [4096][512], B=W_in [1024][512]
  gemm_bt_bias_relu<<<dim3(HID / 64, BATCH / 128), 256, 0, stream>>>(
      xT, Wi, b_in, itm, h0, IN_DIM, HID);

  // 32 recurrent steps
  __hip_bfloat16* cur = h0;
  __hip_bfloat16* nxt = h1;
  for (int t = 0; t < T_STEPS; ++t) {
    float* dst = itm + (size_t)(t + 1) * HID * BATCH;
    gemm_bt_bias_relu<<<dim3(HID / 64, BATCH / 128), 256, 0, stream>>>(
        cur, Wr, b_rec, dst, nxt, HID, HID);
    __hip_bfloat16* tmp = cur; cur = nxt; nxt = tmp;
  }

  // out = relu(W_out @ h_last + b_out): B=W_out [512][1024]
  gemm_bt_bias_relu<<<dim3(OUT_DIM / 64, BATCH / 128), 256, 0, stream>>>(
      cur, Wo, b_out, out0, (__hip_bfloat16*)nullptr, HID, 0);
}